// Round 12
// baseline (81.870 us; speedup 1.0000x reference)
//
#include <hip/hip_runtime.h>
#include <hip/hip_bf16.h>
#include <stdint.h>

typedef unsigned short u16;
typedef unsigned int   u32;
typedef short short8 __attribute__((ext_vector_type(8)));
typedef float f32x4  __attribute__((ext_vector_type(4)));
typedef float f32x2  __attribute__((ext_vector_type(2)));

#define MFMA(a, b, c) __builtin_amdgcn_mfma_f32_16x16x32_bf16((a), (b), (c), 0, 0, 0)

static __device__ __forceinline__ u16 bf_trunc(float x) {
    return (u16)(__builtin_bit_cast(u32, x) >> 16);
}
static __device__ __forceinline__ float bf_to_f(u16 h) {
    u32 b = ((u32)h) << 16; return __builtin_bit_cast(float, b);
}
static __device__ __forceinline__ u16 bf_rne(float x) {
    u32 b = __builtin_bit_cast(u32, x);
    return (u16)((b + 0x7FFF + ((b >> 16) & 1)) >> 16);
}
// packed RNE via HIP intrinsic (low 16 = bf16(a)); extract via memcpy (free)
static __device__ __forceinline__ u32 pk_rne(float a, float b) {
    __hip_bfloat162 r = __float22bfloat162_rn(make_float2(a, b));
    u32 out; __builtin_memcpy(&out, &r, 4); return out;
}

// ---------------------------------------------------------------------------
// prep kernel: weights -> MFMA-B-fragment SINGLE bf16 (RNE) in ws.
// frags 0..191 = {Wq,Wk,Wv} (frag = mat*64 + kt*32 + nt), 192..255 = Wo
// (frag = 192 + kt*4 + nt). elem (frag,lane,j) at frag*512 + l*8 + j.
// B[k][col], k = kt*32 + (l>>4)*8 + j, col = nt*16 + (l&15).
// ---------------------------------------------------------------------------
__global__ __launch_bounds__(512) void prep_weights(
    const float* __restrict__ Wq, const float* __restrict__ Wk,
    const float* __restrict__ Wv, const float* __restrict__ Wo,
    u16* __restrict__ ws)
{
    int idx = blockIdx.x * 512 + threadIdx.x;     // 0..131071
    int frag = idx >> 9;
    int rem  = idx & 511;
    int l    = rem >> 3;
    int j    = rem & 7;
    float v;
    if (frag < 192) {
        int mat = frag >> 6;
        int kt  = (frag >> 5) & 1;
        int nt  = frag & 31;
        int k   = kt * 32 + (l >> 4) * 8 + j;
        int col = nt * 16 + (l & 15);
        const float* W = (mat == 0) ? Wq : ((mat == 1) ? Wk : Wv);
        v = W[k * 512 + col];
    } else {
        int f   = frag - 192;
        int kt  = f >> 2;
        int nt  = f & 3;
        int k   = kt * 32 + (l >> 4) * 8 + j;
        int col = nt * 16 + (l & 15);
        v = Wo[k * 64 + col];
    }
    ws[idx] = bf_rne(v);
}

// ---------------------------------------------------------------------------
// main kernel: 2 patches / block, 512 thr (8 waves). wave w owns maps 2w,2w+1.
// attT = mfma(K, Q); P quarter round-trip PING-PONGED across two 16-row
// buffers so stores(NT+1) overlap PV(NT): bufA = dead q/k slices of the map,
// bufB = dead v slices of BOTH maps (vb for both maps preloaded up front).
// LDS arena (u16, 48 KB):
//   q_pk [0..8191]      : [16 ph][64 c'][8 tok], c' = c ^ h  (single bf16)
//   k_pk [8192..16383]  : same
//   v_b  [16384..24575] : [16 ph][8 n][64 d'],  d' = d ^ ((h^2(n&3))<<3)
// overlays (wave-private, dead slices only):
//   bufA(map pp) rows: 0-7 @ q_pk+ph*512, 8-15 @ k_pk+ph*512
//   bufB (both maps) rows: 0-7 @ v_b+2w*512, 8-15 @ v_b+(2w+1)*512
//   ctxA [16][512] @ q_pk (after barrier); partials f32 4KB @ v_b.
// ---------------------------------------------------------------------------
__global__ __launch_bounds__(512, 4) void fused_attn_mfma(
    const float* __restrict__ emb,
    const u16*  __restrict__ w3,     // 192 qkv frags (single bf16)
    const u16*  __restrict__ wo,     // 64 Wo frags (single bf16)
    float* __restrict__ out)
{
    __shared__ u16 arena[24576];
    u16* q_pk = arena;
    u16* k_pk = arena + 8192;
    u16* v_b  = arena + 16384;

    const int t   = threadIdx.x;
    const int l   = t & 63;
    const int w   = t >> 6;
    const int g   = l >> 4;
    const int l15 = l & 15;
    const int bp2 = blockIdx.x;    // 0..1727

    // ---- P1 A-frags: row m = l15 = p*8 + n, single bf16 RNE ----
    short8 ae[2];
    {
        const float* eb = emb + ((size_t)bp2 * 2 + (l15 >> 3)) * 512 + (l15 & 7) * 64 + g * 8;
        #pragma unroll
        for (int kt = 0; kt < 2; ++kt) {
            float4 e0 = *(const float4*)(eb + kt * 32);
            float4 e1 = *(const float4*)(eb + kt * 32 + 4);
            uint4 pk4;
            pk4.x = pk_rne(e0.x, e0.y);
            pk4.y = pk_rne(e0.z, e0.w);
            pk4.z = pk_rne(e1.x, e1.y);
            pk4.w = pk_rne(e1.z, e1.w);
            ae[kt] = __builtin_bit_cast(short8, pk4);
        }
    }

    // ---- P1: QKV = emb @ {Wq,Wk,Wv}, single x single (2 MFMA/tile) ----
    #pragma unroll
    for (int i = 0; i < 12; ++i) {
        int tid = w * 12 + i;          // 0..95
        int mat = tid >> 5;            // 0=q 1=k 2=v
        int nt  = tid & 31;
        f32x4 acc = {0.f, 0.f, 0.f, 0.f};
        #pragma unroll
        for (int kt = 0; kt < 2; ++kt) {
            const u16* bb = &w3[(mat * 64 + kt * 32 + nt) * 512];
            short8 bh = *(const short8*)&bb[l * 8];
            acc = MFMA(ae[kt], bh, acc);
        }
        int hh = l15 & 7;
        int cc = nt * 2 + (l15 >> 3);
        int p  = g >> 1;
        int ph = p * 8 + hh;
        if (mat < 2) {
            u32 pk0 = pk_rne(acc[0], acc[1]);
            u32 pk1 = pk_rne(acc[2], acc[3]);
            u32 r0 = (u32)__shfl_xor((int)pk0, 16);
            u32 r1 = (u32)__shfl_xor((int)pk1, 16);
            if (!(g & 1)) {
                uint4 row;
                row.x = pk0; row.y = pk1; row.z = r0; row.w = r1;
                u16* base = (mat == 0) ? q_pk : k_pk;
                *(uint4*)&base[(ph * 64 + (cc ^ hh)) * 8] = row;
            }
        } else {
            u32 pkA = pk_rne(acc[0], acc[1]);
            u32 pkB = pk_rne(acc[2], acc[3]);
            u32 send = (l15 & 8) ? pkA : pkB;
            u32 recv = (u32)__shfl_xor((int)send, 8);
            int d0 = nt * 2;
            u32 wA, wB; int rA;
            if (!(l15 & 8)) {
                wA = (pkA & 0xffffu) | ((recv & 0xffffu) << 16);
                wB = (pkA >> 16)     | (recv & 0xffff0000u);
                rA = 0;
            } else {
                wA = (recv & 0xffffu) | ((pkB & 0xffffu) << 16);
                wB = (recv >> 16)     | (pkB & 0xffff0000u);
                rA = 2;
            }
            int nA = (g & 1) * 4 + rA, nB = nA + 1;
            int sA = hh ^ ((nA & 3) << 1), sB = hh ^ ((nB & 3) << 1);
            *(u32*)&v_b[(ph * 8 + nA) * 64 + (d0 ^ (sA << 3))] = wA;
            *(u32*)&v_b[(ph * 8 + nB) * 64 + (d0 ^ (sB << 3))] = wB;
        }
    }
    __syncthreads();

    // ---- P2: two (patch,head) maps per wave ----
    const short8 z8 = {0, 0, 0, 0, 0, 0, 0, 0};
    const short8 ones = {(short)0x3F80, (short)0x3F80, (short)0x3F80, (short)0x3F80,
                         (short)0x3F80, (short)0x3F80, (short)0x3F80, (short)0x3F80};
    const f32x4 zf = {0.f, 0.f, 0.f, 0.f};
    f32x4 ctx[2][4];

    // Preload V B-frags for BOTH maps (frees v slices 2w, 2w+1 as bufB).
    short8 vb2[2][2];
    #pragma unroll
    for (int pp = 0; pp < 2; ++pp) {
        const int ph = 2 * w + pp;
        const int h  = ph & 7;
        int n_  = l15 & 7;
        int sig = h ^ ((n_ & 3) << 1);
        #pragma unroll
        for (int kt = 0; kt < 2; ++kt) {
            short8 x = *(const short8*)&v_b[(ph * 8 + n_) * 64 +
                                            ((kt * 32 + g * 8) ^ (sig << 3))];
            vb2[pp][kt] = (l15 >= 8) ? ones : x;
        }
    }

    // bufB rows (shared across both maps): 0-7 @ v slice 2w, 8-15 @ 2w+1
    u16* rowB = (((l15 < 8) ? (v_b + (2 * w) * 512) : (v_b + (2 * w + 1) * 512))
                 + (l15 & 7) * 64);
    const int swz = (l15 & 7) << 3;

    #pragma unroll
    for (int pp = 0; pp < 2; ++pp) {
        const int ph = 2 * w + pp;
        const int h  = ph & 7;

        // attT = mfma(K, Q): row = d = mt*16+g*4+r, col = c = nt*16+l15
        short8 qb[4];
        #pragma unroll
        for (int nt = 0; nt < 4; ++nt)
            qb[nt] = *(const short8*)&q_pk[(ph * 64 + ((nt * 16 + l15) ^ h)) * 8];

        f32x4 att[4][4];
        __builtin_amdgcn_s_setprio(1);
        #pragma unroll
        for (int mt = 0; mt < 4; ++mt) {
            short8 krow = *(const short8*)&k_pk[(ph * 64 + ((mt * 16 + l15) ^ h)) * 8];
            short8 ka = (g == 0) ? krow : z8;
            #pragma unroll
            for (int nt = 0; nt < 4; ++nt)
                att[mt][nt] = MFMA(ka, qb[nt], zf);
        }
        __builtin_amdgcn_s_setprio(0);

        // instance-norm stats, packed f32 ops
        f32x4 s4 = zf, q4 = zf;
        #pragma unroll
        for (int mt = 0; mt < 4; ++mt)
            #pragma unroll
            for (int nt = 0; nt < 4; ++nt) {
                s4 += att[mt][nt];
                q4 = __builtin_elementwise_fma(att[mt][nt], att[mt][nt], q4);
            }
        f32x2 r2;
        r2[0] = (s4[0] + s4[1]) + (s4[2] + s4[3]);
        r2[1] = (q4[0] + q4[1]) + (q4[2] + q4[3]);
        #pragma unroll
        for (int m = 1; m < 64; m <<= 1) {
            f32x2 o;
            o[0] = __shfl_xor(r2[0], m);
            o[1] = __shfl_xor(r2[1], m);
            r2 += o;
        }
        float mu  = r2[0] * (1.f / 4096.f);
        float var = r2[1] * (1.f / 4096.f) - mu * mu;
        float rsv = rsqrtf(var + 1e-5f) * 1.44269504f;   // rstd*log2e
        float mu2 = mu * rsv;
        f32x4 rs4 = {rsv, rsv, rsv, rsv};
        f32x4 mn4 = {-mu2, -mu2, -mu2, -mu2};

        // exp (mean shift exact-cancels in softmax; |z|<=64 -> no overflow)
        #pragma unroll
        for (int mt = 0; mt < 4; ++mt)
            #pragma unroll
            for (int nt = 0; nt < 4; ++nt) {
                f32x4 tt = __builtin_elementwise_fma(att[mt][nt], rs4, mn4);
                att[mt][nt][0] = __builtin_amdgcn_exp2f(tt[0]);
                att[mt][nt][1] = __builtin_amdgcn_exp2f(tt[1]);
                att[mt][nt][2] = __builtin_amdgcn_exp2f(tt[2]);
                att[mt][nt][3] = __builtin_amdgcn_exp2f(tt[3]);
            }

        // bufA rows for this map: 0-7 @ dead q slice, 8-15 @ dead k slice
        u16* rowA = (((l15 < 8) ? (q_pk + ph * 512) : (k_pk + ph * 512))
                     + (l15 & 7) * 64);

        // PV per c-quarter, ping-pong A/B so stores(NT+1) overlap PV(NT)
        #pragma unroll
        for (int NT = 0; NT < 4; ++NT) {
            u16* rowbase = (NT & 1) ? rowB : rowA;
            #pragma unroll
            for (int mt = 0; mt < 4; ++mt) {
                uint2 b;
                b.x = pk_rne(att[mt][NT][0], att[mt][NT][1]);
                b.y = pk_rne(att[mt][NT][2], att[mt][NT][3]);
                *(uint2*)&rowbase[(mt * 16 + g * 4) ^ swz] = b;
            }
            f32x4 pv = zf;
            __builtin_amdgcn_s_setprio(1);
            #pragma unroll
            for (int kt = 0; kt < 2; ++kt) {
                short8 aa = *(const short8*)&rowbase[(kt * 32 + g * 8) ^ swz];
                pv = MFMA(aa, vb2[pp][kt], pv);
            }
            __builtin_amdgcn_s_setprio(0);
            // normalize: row sums in col 8 -> lane (g<<4)|8
            int srcl = (l & 48) | 8;
            #pragma unroll
            for (int r = 0; r < 4; ++r) {
                float rsum = __shfl(pv[r], srcl);
                pv[r] *= __builtin_amdgcn_rcpf(rsum);
            }
            ctx[pp][NT] = pv;
        }
    }
    __syncthreads();   // all waves done with q/k/v before ctxA overlay

    // ---- ctx -> ctxA [16 m][512 k'] bf16 (k' = (c*8+h) ^ ((m&3)<<4)) ----
    u16* ctxA = arena;   // over q_pk, 8192 u16 exactly
    if (l15 < 8) {
        #pragma unroll
        for (int pp = 0; pp < 2; ++pp) {
            int ph = 2 * w + pp;
            int h  = ph & 7;
            int p  = ph >> 3;
            int m  = p * 8 + l15;
            int swz2 = (m & 3) << 4;
            #pragma unroll
            for (int MT = 0; MT < 4; ++MT) {
                u32 w0 = pk_rne(ctx[pp][MT][0], ctx[pp][MT][1]);
                u32 w1 = pk_rne(ctx[pp][MT][2], ctx[pp][MT][3]);
                int c0 = MT * 16 + g * 4;
                ctxA[m * 512 + (((c0 + 0) * 8 + h) ^ swz2)] = (u16)w0;
                ctxA[m * 512 + (((c0 + 1) * 8 + h) ^ swz2)] = (u16)(w0 >> 16);
                ctxA[m * 512 + (((c0 + 2) * 8 + h) ^ swz2)] = (u16)w1;
                ctxA[m * 512 + (((c0 + 3) * 8 + h) ^ swz2)] = (u16)(w1 >> 16);
            }
        }
    }
    __syncthreads();

    // ---- P3: out = ctx @ Wo (single x single, split-K over wave pairs) ----
    {
        int nt  = w & 3;
        int kb0 = (w >> 2) * 8;
        int m   = l15;
        f32x4 oacc = {0.f, 0.f, 0.f, 0.f};
        #pragma unroll
        for (int ki = 0; ki < 8; ++ki) {
            int kt = kb0 + ki;
            int kk = (kt * 32 + g * 8) ^ ((m & 3) << 4);
            short8 ah = *(const short8*)&ctxA[m * 512 + kk];
            const u16* bb = &wo[(kt * 4 + nt) * 512];
            short8 bh = *(const short8*)&bb[l * 8];
            oacc = MFMA(ah, bh, oacc);
        }
        float* part = (float*)&v_b[0];     // 4 KB over dead v region
        if (w >= 4) *(f32x4*)&part[((w - 4) * 64 + l) * 4] = oacc;
        __syncthreads();
        if (w < 4) {
            f32x4 o2 = *(const f32x4*)&part[(w * 64 + l) * 4];
            oacc += o2;
            int col = nt * 16 + l15;
            int p   = g >> 1;
            int bp  = bp2 * 2 + p;
            int b   = bp / 27, rr = bp % 27;
            int dd  = rr / 9, hh2 = (rr / 3) % 3, ww2 = rr % 3;
            #pragma unroll
            for (int r = 0; r < 4; ++r) {
                int n = (g & 1) * 4 + r;
                int token = ((((dd * 2 + (n >> 2)) * 3 + hh2) * 2 + ((n >> 1) & 1)) * 3
                             + ww2) * 2 + (n & 1);
                out[((size_t)b * 216 + token) * 64 + col] = oacc[r];
            }
        }
    }
}

// ---------------------------------------------------------------------------
// fallback (round-2 kernel) if ws is too small for weight preconversion
// ---------------------------------------------------------------------------
__global__ __launch_bounds__(512) void fused_fallback(
    const float* __restrict__ emb, const float* __restrict__ Wq,
    const float* __restrict__ Wk,  const float* __restrict__ Wv,
    const float* __restrict__ Wo,  float* __restrict__ out)
{
    __shared__ float emb_s[512];
    __shared__ float part_sum[64];
    __shared__ float part_ssq[64];
    __shared__ float kv_s[2 * 512 * 8];
    float* k_s = kv_s;
    float* v_s = kv_s + 512 * 8;
    float* ctx_s = kv_s;
    const int bp = blockIdx.x;
    const int t  = threadIdx.x;
    emb_s[t] = emb[bp * 512 + t];
    __syncthreads();
    float q[8];
    {
        float ak[8], av[8];
        #pragma unroll
        for (int n = 0; n < 8; ++n) { q[n] = 0.f; ak[n] = 0.f; av[n] = 0.f; }
        #pragma unroll 8
        for (int j = 0; j < 64; ++j) {
            const float wq = Wq[j * 512 + t], wk = Wk[j * 512 + t], wv = Wv[j * 512 + t];
            #pragma unroll
            for (int n = 0; n < 8; ++n) {
                const float e = emb_s[n * 64 + j];
                q[n] += e * wq; ak[n] += e * wk; av[n] += e * wv;
            }
        }
        float4* kd = (float4*)&k_s[t * 8];
        float4* vd = (float4*)&v_s[t * 8];
        kd[0] = make_float4(ak[0], ak[1], ak[2], ak[3]);
        kd[1] = make_float4(ak[4], ak[5], ak[6], ak[7]);
        vd[0] = make_float4(av[0], av[1], av[2], av[3]);
        vd[1] = make_float4(av[4], av[5], av[6], av[7]);
    }
    __syncthreads();
    const int h = t & 7;
    float arow[64];
    float sum = 0.f, ssq = 0.f;
    #pragma unroll
    for (int d = 0; d < 64; ++d) {
        const float4* kr = (const float4*)&k_s[(d * 8 + h) * 8];
        const float4 k0 = kr[0], k1 = kr[1];
        float s = q[0]*k0.x + q[1]*k0.y + q[2]*k0.z + q[3]*k0.w
                + q[4]*k1.x + q[5]*k1.y + q[6]*k1.z + q[7]*k1.w;
        arow[d] = s; sum += s; ssq += s * s;
    }
    #pragma unroll
    for (int m = 8; m < 64; m <<= 1) { sum += __shfl_xor(sum, m); ssq += __shfl_xor(ssq, m); }
    const int wv_id = t >> 6;
    if ((t & 63) < 8) { part_sum[wv_id * 8 + h] = sum; part_ssq[wv_id * 8 + h] = ssq; }
    __syncthreads();
    sum = 0.f; ssq = 0.f;
    #pragma unroll
    for (int w2 = 0; w2 < 8; ++w2) { sum += part_sum[w2 * 8 + h]; ssq += part_ssq[w2 * 8 + h]; }
    const float mean = sum * (1.f / 4096.f);
    const float var  = ssq * (1.f / 4096.f) - mean * mean;
    const float rstd = rsqrtf(var + 1e-5f);
    float mx = -3.0e38f;
    #pragma unroll
    for (int d = 0; d < 64; ++d) { arow[d] = (arow[d] - mean) * rstd; mx = fmaxf(mx, arow[d]); }
    float es = 0.f;
    #pragma unroll
    for (int d = 0; d < 64; ++d) { arow[d] = __expf(arow[d] - mx); es += arow[d]; }
    const float inv = 1.f / es;
    float c[8];
    #pragma unroll
    for (int n = 0; n < 8; ++n) c[n] = 0.f;
    #pragma unroll
    for (int d = 0; d < 64; ++d) {
        const float4* vr = (const float4*)&v_s[(d * 8 + h) * 8];
        const float4 v0 = vr[0], v1 = vr[1];
        const float a = arow[d] * inv;
        c[0]+=a*v0.x; c[1]+=a*v0.y; c[2]+=a*v0.z; c[3]+=a*v0.w;
        c[4]+=a*v1.x; c[5]+=a*v1.y; c[6]+=a*v1.z; c[7]+=a*v1.w;
    }
    __syncthreads();
    #pragma unroll
    for (int n = 0; n < 8; ++n) ctx_s[n * 512 + t] = c[n];
    __syncthreads();
    const int n_o = t >> 6, gg = t & 15, ss = (t >> 4) & 3;
    const float4* Wo4 = (const float4*)Wo;
    const float4* cx4 = (const float4*)&ctx_s[n_o * 512 + ss * 128];
    float4 acc = make_float4(0.f, 0.f, 0.f, 0.f);
    #pragma unroll 8
    for (int kk = 0; kk < 128; kk += 4) {
        const float4 cc = cx4[kk >> 2];
        const int kbm = (ss * 128 + kk) * 16 + gg;
        const float4 w0 = Wo4[kbm], w1 = Wo4[kbm + 16], w2 = Wo4[kbm + 32], w3_ = Wo4[kbm + 48];
        acc.x += cc.x*w0.x + cc.y*w1.x + cc.z*w2.x + cc.w*w3_.x;
        acc.y += cc.x*w0.y + cc.y*w1.y + cc.z*w2.y + cc.w*w3_.y;
        acc.z += cc.x*w0.z + cc.y*w1.z + cc.z*w2.z + cc.w*w3_.z;
        acc.w += cc.x*w0.w + cc.y*w1.w + cc.z*w2.w + cc.w*w3_.w;
    }
    acc.x += __shfl_xor(acc.x, 16); acc.x += __shfl_xor(acc.x, 32);
    acc.y += __shfl_xor(acc.y, 16); acc.y += __shfl_xor(acc.y, 32);
    acc.z += __shfl_xor(acc.z, 16); acc.z += __shfl_xor(acc.z, 32);
    acc.w += __shfl_xor(acc.w, 16); acc.w += __shfl_xor(acc.w, 32);
    if (ss == 0) {
        const int b = bp / 27, r = bp % 27;
        const int dd = r / 9, hh = (r / 3) % 3, ww = r % 3;
        const int token = ((((dd*2 + ((n_o>>2)&1))*3 + hh)*2 + ((n_o>>1)&1))*3 + ww)*2 + (n_o&1);
        *(float4*)&out[(b * 216 + token) * 64 + gg * 4] = acc;
    }
}

extern "C" void kernel_launch(void* const* d_in, const int* in_sizes, int n_in,
                              void* d_out, int out_size, void* d_ws, size_t ws_size,
                              hipStream_t stream) {
    const float* emb = (const float*)d_in[0];
    const float* Wq  = (const float*)d_in[1];
    const float* Wk  = (const float*)d_in[2];
    const float* Wv  = (const float*)d_in[3];
    const float* Wo  = (const float*)d_in[4];
    float* out = (float*)d_out;
    const int Bp = in_sizes[0] / 512;   // 3456

    if (ws_size >= 131072 * sizeof(u16) && (Bp & 1) == 0) {
        u16* ws = (u16*)d_ws;
        prep_weights<<<256, 512, 0, stream>>>(Wq, Wk, Wv, Wo, ws);
        fused_attn_mfma<<<Bp / 2, 512, 0, stream>>>(emb, ws, ws + 98304, out);
    } else {
        fused_fallback<<<Bp, 512, 0, stream>>>(emb, Wq, Wk, Wv, Wo, out);
    }
}

// Round 13
// 60.871 us; speedup vs baseline: 1.3450x; 1.3450x over previous
//
#include <hip/hip_runtime.h>
#include <hip/hip_bf16.h>
#include <stdint.h>

typedef unsigned short u16;
typedef unsigned int   u32;
typedef short short8 __attribute__((ext_vector_type(8)));
typedef float f32x4  __attribute__((ext_vector_type(4)));
typedef float f32x2  __attribute__((ext_vector_type(2)));

#define MFMA(a, b, c) __builtin_amdgcn_mfma_f32_16x16x32_bf16((a), (b), (c), 0, 0, 0)

static __device__ __forceinline__ u16 bf_trunc(float x) {
    return (u16)(__builtin_bit_cast(u32, x) >> 16);
}
static __device__ __forceinline__ float bf_to_f(u16 h) {
    u32 b = ((u32)h) << 16; return __builtin_bit_cast(float, b);
}
static __device__ __forceinline__ u16 bf_rne(float x) {
    u32 b = __builtin_bit_cast(u32, x);
    return (u16)((b + 0x7FFF + ((b >> 16) & 1)) >> 16);
}
// packed RNE via HIP intrinsic (low 16 = bf16(a)); extract via memcpy (free)
static __device__ __forceinline__ u32 pk_rne(float a, float b) {
    __hip_bfloat162 r = __float22bfloat162_rn(make_float2(a, b));
    u32 out; __builtin_memcpy(&out, &r, 4); return out;
}

// ---------------------------------------------------------------------------
// prep kernel: weights -> MFMA-B-fragment SINGLE bf16 (RNE) in ws, with
// HEAD-MAJOR column permutation for qkv: new col = h*64 + c (so tile nt
// covers head nt>>2 entirely; wave w owns tiles 4w..4w+3 of each matrix).
// frags 0..191 = {Wq,Wk,Wv} (frag = mat*64 + kt*32 + nt), 192..255 = Wo
// (frag = 192 + kt*4 + nt, unpermuted). elem (frag,lane,j) at frag*512+l*8+j.
// qkv: B[k][colnew], k = kt*32 + (l>>4)*8 + j, colnew = nt*16 + (l&15),
//      src col = c*8 + h with h = nt>>2, c = (nt&3)*16 + (l&15).
// ---------------------------------------------------------------------------
__global__ __launch_bounds__(512) void prep_weights(
    const float* __restrict__ Wq, const float* __restrict__ Wk,
    const float* __restrict__ Wv, const float* __restrict__ Wo,
    u16* __restrict__ ws)
{
    int idx = blockIdx.x * 512 + threadIdx.x;     // 0..131071
    int frag = idx >> 9;
    int rem  = idx & 511;
    int l    = rem >> 3;
    int j    = rem & 7;
    float v;
    if (frag < 192) {
        int mat = frag >> 6;
        int kt  = (frag >> 5) & 1;
        int nt  = frag & 31;
        int k   = kt * 32 + (l >> 4) * 8 + j;
        int h   = nt >> 2;
        int c   = (nt & 3) * 16 + (l & 15);
        const float* W = (mat == 0) ? Wq : ((mat == 1) ? Wk : Wv);
        v = W[k * 512 + c * 8 + h];
    } else {
        int f   = frag - 192;
        int kt  = f >> 2;
        int nt  = f & 3;
        int k   = kt * 32 + (l >> 4) * 8 + j;
        int col = nt * 16 + (l & 15);
        v = Wo[k * 64 + col];
    }
    ws[idx] = bf_rne(v);
}

// ---------------------------------------------------------------------------
// main kernel: 2 patches / block, 512 thr (8 waves). HEAD-MAJOR ownership:
// wave w owns head w for BOTH patches (maps (p=0,h=w), (p=1,h=w)), and all
// its q/k/v is produced by ITSELF in P1 -> wave-private LDS, NO barrier
// between P1 and P2 (per-wave DS ops are in-order).
// LDS arena (u16, 48 KB), per-wave slices (base + w*1024):
//   q_w [0..8191]      : per wave [2 p][64 c][8 tok]  (single bf16)
//   k_w [8192..16383]  : same
//   v_w [16384..24575] : per wave [2 p][8 n][64 d'], d' = d ^ ((n&3)<<4)
// overlays:
//   PV quarter buffer [16 c-rows][64 d] per map pp: rows 0-7 = q_w slice of
//   patch pp (dead after qb loads), rows 8-15 = k_w slice (dead after QK);
//   col swizzle ^((l15&7)<<3) (b64/b128-safe).
//   ctxA [16 m][512 k'] @ arena[0..8191] (after barrier); partials @ v region.
// ---------------------------------------------------------------------------
__global__ __launch_bounds__(512, 4) void fused_attn_mfma(
    const float* __restrict__ emb,
    const u16*  __restrict__ w3,     // 192 qkv frags (single bf16, head-major)
    const u16*  __restrict__ wo,     // 64 Wo frags (single bf16)
    float* __restrict__ out)
{
    __shared__ u16 arena[24576];

    const int t   = threadIdx.x;
    const int l   = t & 63;
    const int w   = t >> 6;
    const int g   = l >> 4;
    const int l15 = l & 15;
    const int bp2 = blockIdx.x;    // 0..1727

    u16* q_w = arena + w * 1024;            // [2][64][8]
    u16* k_w = arena + 8192 + w * 1024;     // [2][64][8]
    u16* v_w = arena + 16384 + w * 1024;    // [2][8][64]

    // ---- P1 A-frags: row m = l15 = p*8 + n, single bf16 RNE ----
    short8 ae[2];
    {
        const float* eb = emb + ((size_t)bp2 * 2 + (l15 >> 3)) * 512 + (l15 & 7) * 64 + g * 8;
        #pragma unroll
        for (int kt = 0; kt < 2; ++kt) {
            float4 e0 = *(const float4*)(eb + kt * 32);
            float4 e1 = *(const float4*)(eb + kt * 32 + 4);
            uint4 pk4;
            pk4.x = pk_rne(e0.x, e0.y);
            pk4.y = pk_rne(e0.z, e0.w);
            pk4.z = pk_rne(e1.x, e1.y);
            pk4.w = pk_rne(e1.z, e1.w);
            ae[kt] = __builtin_bit_cast(short8, pk4);
        }
    }

    // ---- P1: wave w computes head w's q/k/v tiles (4 each), 2 patches ----
    #pragma unroll
    for (int i = 0; i < 12; ++i) {
        int mat = i >> 2;              // 0=q 1=k 2=v
        int ct  = i & 3;               // channel block within head
        int nt  = w * 4 + ct;          // head-major tile id
        f32x4 acc = {0.f, 0.f, 0.f, 0.f};
        #pragma unroll
        for (int kt = 0; kt < 2; ++kt) {
            const u16* bb = &w3[(mat * 64 + kt * 32 + nt) * 512];
            short8 bh = *(const short8*)&bb[l * 8];
            acc = MFMA(ae[kt], bh, acc);
        }
        // C/D: col l15 -> channel c = ct*16+l15 (of head w);
        // rows g*4+r -> p = g>>1, n = (g&1)*4 + r  (4 consecutive tokens!)
        int p = g >> 1;
        if (mat < 2) {
            // direct b64 store: tokens n0..n0+3 of (p, c) — no lane exchange
            int c = ct * 16 + l15;
            uint2 b;
            b.x = pk_rne(acc[0], acc[1]);
            b.y = pk_rne(acc[2], acc[3]);
            u16* base = (mat == 0) ? q_w : k_w;
            *(uint2*)&base[p * 512 + c * 8 + (g & 1) * 4] = b;
        } else {
            // v: pair adjacent d columns via lane^1 -> u32 stores
            int d0 = ct * 16 + (l15 & ~1);
            u32 pkA = pk_rne(acc[0], acc[1]);   // tokens r0,r1 (col d = ct*16+l15)
            u32 pkB = pk_rne(acc[2], acc[3]);   // tokens r2,r3
            u32 send = (l15 & 1) ? pkA : pkB;
            u32 recv = (u32)__shfl_xor((int)send, 1);
            u32 wA, wB; int rA;
            if (!(l15 & 1)) {   // even lane: own col d0; writes tokens r0,r1
                wA = (pkA & 0xffffu) | ((recv & 0xffffu) << 16);
                wB = (pkA >> 16)     | (recv & 0xffff0000u);
                rA = 0;
            } else {            // odd lane: own col d0+1; writes tokens r2,r3
                wA = (recv & 0xffffu) | ((pkB & 0xffffu) << 16);
                wB = (recv >> 16)     | (pkB & 0xffff0000u);
                rA = 2;
            }
            int nA = (g & 1) * 4 + rA, nB = nA + 1;
            *(u32*)&v_w[p * 512 + nA * 64 + (d0 ^ ((nA & 3) << 4))] = wA;
            *(u32*)&v_w[p * 512 + nB * 64 + (d0 ^ ((nB & 3) << 4))] = wB;
        }
    }
    // NO __syncthreads: all P1->P2 dataflow is wave-private (in-order DS).

    // ---- P2: two maps per wave: (p=0,h=w), (p=1,h=w) ----
    const short8 z8 = {0, 0, 0, 0, 0, 0, 0, 0};
    const short8 ones = {(short)0x3F80, (short)0x3F80, (short)0x3F80, (short)0x3F80,
                         (short)0x3F80, (short)0x3F80, (short)0x3F80, (short)0x3F80};
    const f32x4 zf = {0.f, 0.f, 0.f, 0.f};
    f32x4 ctx[2][4];

    #pragma unroll
    for (int pp = 0; pp < 2; ++pp) {
        // attT = mfma(K, Q): row = d = mt*16+g*4+r, col = c = nt*16+l15
        short8 qb[4];
        #pragma unroll
        for (int nt = 0; nt < 4; ++nt)
            qb[nt] = *(const short8*)&q_w[pp * 512 + (nt * 16 + l15) * 8];

        f32x4 att[4][4];
        __builtin_amdgcn_s_setprio(1);
        #pragma unroll
        for (int mt = 0; mt < 4; ++mt) {
            short8 krow = *(const short8*)&k_w[pp * 512 + (mt * 16 + l15) * 8];
            short8 ka = (g == 0) ? krow : z8;
            #pragma unroll
            for (int nt = 0; nt < 4; ++nt)
                att[mt][nt] = MFMA(ka, qb[nt], zf);
        }
        __builtin_amdgcn_s_setprio(0);

        // instance-norm stats, packed f32 ops
        f32x4 s4 = zf, q4 = zf;
        #pragma unroll
        for (int mt = 0; mt < 4; ++mt)
            #pragma unroll
            for (int nt = 0; nt < 4; ++nt) {
                s4 += att[mt][nt];
                q4 = __builtin_elementwise_fma(att[mt][nt], att[mt][nt], q4);
            }
        f32x2 r2;
        r2[0] = (s4[0] + s4[1]) + (s4[2] + s4[3]);
        r2[1] = (q4[0] + q4[1]) + (q4[2] + q4[3]);
        #pragma unroll
        for (int m = 1; m < 64; m <<= 1) {
            f32x2 o;
            o[0] = __shfl_xor(r2[0], m);
            o[1] = __shfl_xor(r2[1], m);
            r2 += o;
        }
        float mu  = r2[0] * (1.f / 4096.f);
        float var = r2[1] * (1.f / 4096.f) - mu * mu;
        float rsv = rsqrtf(var + 1e-5f) * 1.44269504f;   // rstd*log2e
        float mu2 = mu * rsv;
        f32x4 rs4 = {rsv, rsv, rsv, rsv};
        f32x4 mn4 = {-mu2, -mu2, -mu2, -mu2};

        // exp (mean shift exact-cancels in softmax; |z|<=64 -> no overflow)
        #pragma unroll
        for (int mt = 0; mt < 4; ++mt)
            #pragma unroll
            for (int nt = 0; nt < 4; ++nt) {
                f32x4 tt = __builtin_elementwise_fma(att[mt][nt], rs4, mn4);
                att[mt][nt][0] = __builtin_amdgcn_exp2f(tt[0]);
                att[mt][nt][1] = __builtin_amdgcn_exp2f(tt[1]);
                att[mt][nt][2] = __builtin_amdgcn_exp2f(tt[2]);
                att[mt][nt][3] = __builtin_amdgcn_exp2f(tt[3]);
            }

        // V B-frags for this map; cols 8+ = ones (row-sum column)
        short8 vb[2];
        {
            int n_ = l15 & 7;
            #pragma unroll
            for (int kt = 0; kt < 2; ++kt) {
                short8 x = *(const short8*)&v_w[pp * 512 + n_ * 64 +
                                                ((kt * 32 + g * 8) ^ ((n_ & 3) << 4))];
                vb[kt] = (l15 >= 8) ? ones : x;
            }
        }

        // PV per c-quarter through this map's dead q/k slices (R11 pattern)
        u16* rowbase = (((l15 < 8) ? (q_w + pp * 512) : (k_w + pp * 512))
                        + (l15 & 7) * 64);
        const int swz = (l15 & 7) << 3;
        #pragma unroll
        for (int NT = 0; NT < 4; ++NT) {
            #pragma unroll
            for (int mt = 0; mt < 4; ++mt) {
                uint2 b;
                b.x = pk_rne(att[mt][NT][0], att[mt][NT][1]);
                b.y = pk_rne(att[mt][NT][2], att[mt][NT][3]);
                *(uint2*)&rowbase[(mt * 16 + g * 4) ^ swz] = b;
            }
            f32x4 pv = zf;
            __builtin_amdgcn_s_setprio(1);
            #pragma unroll
            for (int kt = 0; kt < 2; ++kt) {
                short8 aa = *(const short8*)&rowbase[(kt * 32 + g * 8) ^ swz];
                pv = MFMA(aa, vb[kt], pv);
            }
            __builtin_amdgcn_s_setprio(0);
            // normalize: row sums in col 8 -> lane (g<<4)|8
            int srcl = (l & 48) | 8;
            #pragma unroll
            for (int r = 0; r < 4; ++r) {
                float rsum = __shfl(pv[r], srcl);
                pv[r] *= __builtin_amdgcn_rcpf(rsum);
            }
            ctx[pp][NT] = pv;
        }
    }
    __syncthreads();   // all waves done with their slices before ctxA overlay

    // ---- ctx -> ctxA [16 m][512 k'] bf16 (k' = (c*8+h) ^ ((m&3)<<4)), h=w ----
    u16* ctxA = arena;   // over the whole q region, 8192 u16
    if (l15 < 8) {
        #pragma unroll
        for (int pp = 0; pp < 2; ++pp) {
            int m = pp * 8 + l15;
            int swz2 = (m & 3) << 4;
            #pragma unroll
            for (int MT = 0; MT < 4; ++MT) {
                u32 w0 = pk_rne(ctx[pp][MT][0], ctx[pp][MT][1]);
                u32 w1 = pk_rne(ctx[pp][MT][2], ctx[pp][MT][3]);
                int c0 = MT * 16 + g * 4;
                ctxA[m * 512 + (((c0 + 0) * 8 + w) ^ swz2)] = (u16)w0;
                ctxA[m * 512 + (((c0 + 1) * 8 + w) ^ swz2)] = (u16)(w0 >> 16);
                ctxA[m * 512 + (((c0 + 2) * 8 + w) ^ swz2)] = (u16)w1;
                ctxA[m * 512 + (((c0 + 3) * 8 + w) ^ swz2)] = (u16)(w1 >> 16);
            }
        }
    }
    __syncthreads();

    // ---- P3: out = ctx @ Wo (single x single, split-K over wave pairs) ----
    {
        int nt  = w & 3;
        int kb0 = (w >> 2) * 8;
        int m   = l15;
        f32x4 oacc = {0.f, 0.f, 0.f, 0.f};
        #pragma unroll
        for (int ki = 0; ki < 8; ++ki) {
            int kt = kb0 + ki;
            int kk = (kt * 32 + g * 8) ^ ((m & 3) << 4);
            short8 ah = *(const short8*)&ctxA[m * 512 + kk];
            const u16* bb = &wo[(kt * 4 + nt) * 512];
            short8 bh = *(const short8*)&bb[l * 8];
            oacc = MFMA(ah, bh, oacc);
        }
        float* part = (float*)&arena[16384];   // 4 KB over dead v region
        if (w >= 4) *(f32x4*)&part[((w - 4) * 64 + l) * 4] = oacc;
        __syncthreads();
        if (w < 4) {
            f32x4 o2 = *(const f32x4*)&part[(w * 64 + l) * 4];
            oacc += o2;
            int col = nt * 16 + l15;
            int p   = g >> 1;
            int bp  = bp2 * 2 + p;
            int b   = bp / 27, rr = bp % 27;
            int dd  = rr / 9, hh2 = (rr / 3) % 3, ww2 = rr % 3;
            #pragma unroll
            for (int r = 0; r < 4; ++r) {
                int n = (g & 1) * 4 + r;
                int token = ((((dd * 2 + (n >> 2)) * 3 + hh2) * 2 + ((n >> 1) & 1)) * 3
                             + ww2) * 2 + (n & 1);
                out[((size_t)b * 216 + token) * 64 + col] = oacc[r];
            }
        }
    }
}

// ---------------------------------------------------------------------------
// fallback (round-2 kernel) if ws is too small for weight preconversion
// ---------------------------------------------------------------------------
__global__ __launch_bounds__(512) void fused_fallback(
    const float* __restrict__ emb, const float* __restrict__ Wq,
    const float* __restrict__ Wk,  const float* __restrict__ Wv,
    const float* __restrict__ Wo,  float* __restrict__ out)
{
    __shared__ float emb_s[512];
    __shared__ float part_sum[64];
    __shared__ float part_ssq[64];
    __shared__ float kv_s[2 * 512 * 8];
    float* k_s = kv_s;
    float* v_s = kv_s + 512 * 8;
    float* ctx_s = kv_s;
    const int bp = blockIdx.x;
    const int t  = threadIdx.x;
    emb_s[t] = emb[bp * 512 + t];
    __syncthreads();
    float q[8];
    {
        float ak[8], av[8];
        #pragma unroll
        for (int n = 0; n < 8; ++n) { q[n] = 0.f; ak[n] = 0.f; av[n] = 0.f; }
        #pragma unroll 8
        for (int j = 0; j < 64; ++j) {
            const float wq = Wq[j * 512 + t], wk = Wk[j * 512 + t], wv = Wv[j * 512 + t];
            #pragma unroll
            for (int n = 0; n < 8; ++n) {
                const float e = emb_s[n * 64 + j];
                q[n] += e * wq; ak[n] += e * wk; av[n] += e * wv;
            }
        }
        float4* kd = (float4*)&k_s[t * 8];
        float4* vd = (float4*)&v_s[t * 8];
        kd[0] = make_float4(ak[0], ak[1], ak[2], ak[3]);
        kd[1] = make_float4(ak[4], ak[5], ak[6], ak[7]);
        vd[0] = make_float4(av[0], av[1], av[2], av[3]);
        vd[1] = make_float4(av[4], av[5], av[6], av[7]);
    }
    __syncthreads();
    const int h = t & 7;
    float arow[64];
    float sum = 0.f, ssq = 0.f;
    #pragma unroll
    for (int d = 0; d < 64; ++d) {
        const float4* kr = (const float4*)&k_s[(d * 8 + h) * 8];
        const float4 k0 = kr[0], k1 = kr[1];
        float s = q[0]*k0.x + q[1]*k0.y + q[2]*k0.z + q[3]*k0.w
                + q[4]*k1.x + q[5]*k1.y + q[6]*k1.z + q[7]*k1.w;
        arow[d] = s; sum += s; ssq += s * s;
    }
    #pragma unroll
    for (int m = 8; m < 64; m <<= 1) { sum += __shfl_xor(sum, m); ssq += __shfl_xor(ssq, m); }
    const int wv_id = t >> 6;
    if ((t & 63) < 8) { part_sum[wv_id * 8 + h] = sum; part_ssq[wv_id * 8 + h] = ssq; }
    __syncthreads();
    sum = 0.f; ssq = 0.f;
    #pragma unroll
    for (int w2 = 0; w2 < 8; ++w2) { sum += part_sum[w2 * 8 + h]; ssq += part_ssq[w2 * 8 + h]; }
    const float mean = sum * (1.f / 4096.f);
    const float var  = ssq * (1.f / 4096.f) - mean * mean;
    const float rstd = rsqrtf(var + 1e-5f);
    float mx = -3.0e38f;
    #pragma unroll
    for (int d = 0; d < 64; ++d) { arow[d] = (arow[d] - mean) * rstd; mx = fmaxf(mx, arow[d]); }
    float es = 0.f;
    #pragma unroll
    for (int d = 0; d < 64; ++d) { arow[d] = __expf(arow[d] - mx); es += arow[d]; }
    const float inv = 1.f / es;
    float c[8];
    #pragma unroll
    for (int n = 0; n < 8; ++n) c[n] = 0.f;
    #pragma unroll
    for (int d = 0; d < 64; ++d) {
        const float4* vr = (const float4*)&v_s[(d * 8 + h) * 8];
        const float4 v0 = vr[0], v1 = vr[1];
        const float a = arow[d] * inv;
        c[0]+=a*v0.x; c[1]+=a*v0.y; c[2]+=a*v0.z; c[3]+=a*v0.w;
        c[4]+=a*v1.x; c[5]+=a*v1.y; c[6]+=a*v1.z; c[7]+=a*v1.w;
    }
    __syncthreads();
    #pragma unroll
    for (int n = 0; n < 8; ++n) ctx_s[n * 512 + t] = c[n];
    __syncthreads();
    const int n_o = t >> 6, gg = t & 15, ss = (t >> 4) & 3;
    const float4* Wo4 = (const float4*)Wo;
    const float4* cx4 = (const float4*)&ctx_s[n_o * 512 + ss * 128];
    float4 acc = make_float4(0.f, 0.f, 0.f, 0.f);
    #pragma unroll 8
    for (int kk = 0; kk < 128; kk += 4) {
        const float4 cc = cx4[kk >> 2];
        const int kbm = (ss * 128 + kk) * 16 + gg;
        const float4 w0 = Wo4[kbm], w1 = Wo4[kbm + 16], w2 = Wo4[kbm + 32], w3_ = Wo4[kbm + 48];
        acc.x += cc.x*w0.x + cc.y*w1.x + cc.z*w2.x + cc.w*w3_.x;
        acc.y += cc.x*w0.y + cc.y*w1.y + cc.z*w2.y + cc.w*w3_.y;
        acc.z += cc.x*w0.z + cc.y*w1.z + cc.z*w2.z + cc.w*w3_.z;
        acc.w += cc.x*w0.w + cc.y*w1.w + cc.z*w2.w + cc.w*w3_.w;
    }
    acc.x += __shfl_xor(acc.x, 16); acc.x += __shfl_xor(acc.x, 32);
    acc.y += __shfl_xor(acc.y, 16); acc.y += __shfl_xor(acc.y, 32);
    acc.z += __shfl_xor(acc.z, 16); acc.z += __shfl_xor(acc.z, 32);
    acc.w += __shfl_xor(acc.w, 16); acc.w += __shfl_xor(acc.w, 32);
    if (ss == 0) {
        const int b = bp / 27, r = bp % 27;
        const int dd = r / 9, hh = (r / 3) % 3, ww = r % 3;
        const int token = ((((dd*2 + ((n_o>>2)&1))*3 + hh)*2 + ((n_o>>1)&1))*3 + ww)*2 + (n_o&1);
        *(float4*)&out[(b * 216 + token) * 64 + gg * 4] = acc;
    }
}

extern "C" void kernel_launch(void* const* d_in, const int* in_sizes, int n_in,
                              void* d_out, int out_size, void* d_ws, size_t ws_size,
                              hipStream_t stream) {
    const float* emb = (const float*)d_in[0];
    const float* Wq  = (const float*)d_in[1];
    const float* Wk  = (const float*)d_in[2];
    const float* Wv  = (const float*)d_in[3];
    const float* Wo  = (const float*)d_in[4];
    float* out = (float*)d_out;
    const int Bp = in_sizes[0] / 512;   // 3456

    if (ws_size >= 131072 * sizeof(u16) && (Bp & 1) == 0) {
        u16* ws = (u16*)d_ws;
        prep_weights<<<256, 512, 0, stream>>>(Wq, Wk, Wv, Wo, ws);
        fused_attn_mfma<<<Bp / 2, 512, 0, stream>>>(emb, ws, ws + 98304, out);
    } else {
        fused_fallback<<<Bp, 512, 0, stream>>>(emb, Wq, Wk, Wv, Wo, out);
    }
}

// Round 14
// 60.579 us; speedup vs baseline: 1.3515x; 1.0048x over previous
//
#include <hip/hip_runtime.h>
#include <hip/hip_bf16.h>
#include <stdint.h>

typedef unsigned short u16;
typedef unsigned int   u32;
typedef short short8 __attribute__((ext_vector_type(8)));
typedef float f32x4  __attribute__((ext_vector_type(4)));
typedef float f32x2  __attribute__((ext_vector_type(2)));

#define MFMA(a, b, c) __builtin_amdgcn_mfma_f32_16x16x32_bf16((a), (b), (c), 0, 0, 0)

static __device__ __forceinline__ u16 bf_rne(float x) {
    u32 b = __builtin_bit_cast(u32, x);
    return (u16)((b + 0x7FFF + ((b >> 16) & 1)) >> 16);
}
// packed RNE via HIP intrinsic (low 16 = bf16(a)); extract via memcpy (free)
static __device__ __forceinline__ u32 pk_rne(float a, float b) {
    __hip_bfloat162 r = __float22bfloat162_rn(make_float2(a, b));
    u32 out; __builtin_memcpy(&out, &r, 4); return out;
}

// ---------------------------------------------------------------------------
// prep kernel: weights -> MFMA-B-fragment SINGLE bf16 (RNE) in ws.
// qkv frags 0..191 (frag = mat*64 + kt*32 + nt): HEAD-MAJOR columns,
//   colnew = h*64 + c  (h = nt>>2, c = (nt&3)*16 + (l&15)) -> src col c*8+h.
// Wo frags 192..255 (frag = 192 + kt*4 + nt): HEAD-MAJOR ROWS,
//   k_new = h*64 + c -> src row c*8 + h  (h = k>>6, c = k&63).
// elem (frag,lane,j) at frag*512 + l*8 + j; k = kt*32 + (l>>4)*8 + j.
// ---------------------------------------------------------------------------
__global__ __launch_bounds__(512) void prep_weights(
    const float* __restrict__ Wq, const float* __restrict__ Wk,
    const float* __restrict__ Wv, const float* __restrict__ Wo,
    u16* __restrict__ ws)
{
    int idx = blockIdx.x * 512 + threadIdx.x;     // 0..131071
    int frag = idx >> 9;
    int rem  = idx & 511;
    int l    = rem >> 3;
    int j    = rem & 7;
    float v;
    if (frag < 192) {
        int mat = frag >> 6;
        int kt  = (frag >> 5) & 1;
        int nt  = frag & 31;
        int k   = kt * 32 + (l >> 4) * 8 + j;
        int h   = nt >> 2;
        int c   = (nt & 3) * 16 + (l & 15);
        const float* W = (mat == 0) ? Wq : ((mat == 1) ? Wk : Wv);
        v = W[k * 512 + c * 8 + h];
    } else {
        int f   = frag - 192;
        int kt  = f >> 2;
        int nt  = f & 3;
        int k   = kt * 32 + (l >> 4) * 8 + j;   // k_new (head-major)
        int row = (k & 63) * 8 + (k >> 6);      // src row = c*8 + h
        int col = nt * 16 + (l & 15);
        v = Wo[row * 64 + col];
    }
    ws[idx] = bf_rne(v);
}

// ---------------------------------------------------------------------------
// main kernel: 2 patches / block, 512 thr (8 waves). HEAD-MAJOR everywhere:
// wave w owns head w for both patches; P1 -> P2 wave-private (no barrier);
// ctxA is per-wave STRIPES (wave-private writes, no P2-end barrier).
// LDS arena (u16, 48 KB), per-wave slices (base + w*1024):
//   q_w [0..8191]      : [2 p][64 c][8 tok]  (single bf16)
//   k_w [8192..16383]  : same
//   v_w [16384..24575] : [2 p][8 n][64 d'], d' = d ^ ((n&3)<<4)
// overlays:
//   PV quarter buffer per map pp: rows 0-7 @ q_w+pp*512, rows 8-15 @
//   k_w+pp*512 (dead), col swizzle ^((l15&7)<<3).
//   ctxA stripe w @ q_w (= arena + w*1024): [16 m][64 c], c ^ ((m&7)<<3).
//   partials f32 4KB @ v region (after barrier).
// Barriers: ONE before P3 (cross-wave ctxA reads), ONE before partials-add.
// ---------------------------------------------------------------------------
__global__ __launch_bounds__(512, 4) void fused_attn_mfma(
    const float* __restrict__ emb,
    const u16*  __restrict__ w3,     // 192 qkv frags (single bf16, head-major)
    const u16*  __restrict__ wo,     // 64 Wo frags (single bf16, head-major K)
    float* __restrict__ out)
{
    __shared__ u16 arena[24576];

    const int t   = threadIdx.x;
    const int l   = t & 63;
    const int w   = t >> 6;
    const int g   = l >> 4;
    const int l15 = l & 15;
    const int bp2 = blockIdx.x;    // 0..1727

    u16* q_w = arena + w * 1024;            // [2][64][8]
    u16* k_w = arena + 8192 + w * 1024;     // [2][64][8]
    u16* v_w = arena + 16384 + w * 1024;    // [2][8][64]

    // ---- P1 A-frags: row m = l15 = p*8 + n, single bf16 RNE ----
    short8 ae[2];
    {
        const float* eb = emb + ((size_t)bp2 * 2 + (l15 >> 3)) * 512 + (l15 & 7) * 64 + g * 8;
        #pragma unroll
        for (int kt = 0; kt < 2; ++kt) {
            float4 e0 = *(const float4*)(eb + kt * 32);
            float4 e1 = *(const float4*)(eb + kt * 32 + 4);
            uint4 pk4;
            pk4.x = pk_rne(e0.x, e0.y);
            pk4.y = pk_rne(e0.z, e0.w);
            pk4.z = pk_rne(e1.x, e1.y);
            pk4.w = pk_rne(e1.z, e1.w);
            ae[kt] = __builtin_bit_cast(short8, pk4);
        }
    }

    // ---- P1: wave w computes head w's q/k/v tiles (4 each), 2 patches ----
    #pragma unroll
    for (int i = 0; i < 12; ++i) {
        int mat = i >> 2;              // 0=q 1=k 2=v
        int ct  = i & 3;               // channel block within head
        int nt  = w * 4 + ct;          // head-major tile id
        f32x4 acc = {0.f, 0.f, 0.f, 0.f};
        #pragma unroll
        for (int kt = 0; kt < 2; ++kt) {
            const u16* bb = &w3[(mat * 64 + kt * 32 + nt) * 512];
            short8 bh = *(const short8*)&bb[l * 8];
            acc = MFMA(ae[kt], bh, acc);
        }
        // C/D: col l15 -> channel c = ct*16+l15 (of head w);
        // rows g*4+r -> p = g>>1, n = (g&1)*4 + r  (4 consecutive tokens)
        int p = g >> 1;
        if (mat < 2) {
            int c = ct * 16 + l15;
            uint2 b;
            b.x = pk_rne(acc[0], acc[1]);
            b.y = pk_rne(acc[2], acc[3]);
            u16* base = (mat == 0) ? q_w : k_w;
            *(uint2*)&base[p * 512 + c * 8 + (g & 1) * 4] = b;
        } else {
            // v: pair adjacent d columns via lane^1 -> u32 stores
            int d0 = ct * 16 + (l15 & ~1);
            u32 pkA = pk_rne(acc[0], acc[1]);
            u32 pkB = pk_rne(acc[2], acc[3]);
            u32 send = (l15 & 1) ? pkA : pkB;
            u32 recv = (u32)__shfl_xor((int)send, 1);
            u32 wA, wB; int rA;
            if (!(l15 & 1)) {
                wA = (pkA & 0xffffu) | ((recv & 0xffffu) << 16);
                wB = (pkA >> 16)     | (recv & 0xffff0000u);
                rA = 0;
            } else {
                wA = (recv & 0xffffu) | ((pkB & 0xffffu) << 16);
                wB = (recv >> 16)     | (pkB & 0xffff0000u);
                rA = 2;
            }
            int nA = (g & 1) * 4 + rA, nB = nA + 1;
            *(u32*)&v_w[p * 512 + nA * 64 + (d0 ^ ((nA & 3) << 4))] = wA;
            *(u32*)&v_w[p * 512 + nB * 64 + (d0 ^ ((nB & 3) << 4))] = wB;
        }
    }
    // NO __syncthreads: all P1->P2 dataflow is wave-private (in-order DS).

    // ---- P2: two maps per wave: (p=0,h=w), (p=1,h=w) ----
    const short8 z8 = {0, 0, 0, 0, 0, 0, 0, 0};
    const short8 ones = {(short)0x3F80, (short)0x3F80, (short)0x3F80, (short)0x3F80,
                         (short)0x3F80, (short)0x3F80, (short)0x3F80, (short)0x3F80};
    const f32x4 zf = {0.f, 0.f, 0.f, 0.f};
    f32x4 ctx[2][4];

    #pragma unroll
    for (int pp = 0; pp < 2; ++pp) {
        // attT = mfma(K, Q): row = d = mt*16+g*4+r, col = c = nt*16+l15
        short8 qb[4];
        #pragma unroll
        for (int nt = 0; nt < 4; ++nt)
            qb[nt] = *(const short8*)&q_w[pp * 512 + (nt * 16 + l15) * 8];

        f32x4 att[4][4];
        __builtin_amdgcn_s_setprio(1);
        #pragma unroll
        for (int mt = 0; mt < 4; ++mt) {
            short8 krow = *(const short8*)&k_w[pp * 512 + (mt * 16 + l15) * 8];
            short8 ka = (g == 0) ? krow : z8;
            #pragma unroll
            for (int nt = 0; nt < 4; ++nt)
                att[mt][nt] = MFMA(ka, qb[nt], zf);
        }
        __builtin_amdgcn_s_setprio(0);

        // instance-norm stats, packed f32 ops
        f32x4 s4 = zf, q4 = zf;
        #pragma unroll
        for (int mt = 0; mt < 4; ++mt)
            #pragma unroll
            for (int nt = 0; nt < 4; ++nt) {
                s4 += att[mt][nt];
                q4 = __builtin_elementwise_fma(att[mt][nt], att[mt][nt], q4);
            }
        f32x2 r2;
        r2[0] = (s4[0] + s4[1]) + (s4[2] + s4[3]);
        r2[1] = (q4[0] + q4[1]) + (q4[2] + q4[3]);
        #pragma unroll
        for (int m = 1; m < 64; m <<= 1) {
            f32x2 o;
            o[0] = __shfl_xor(r2[0], m);
            o[1] = __shfl_xor(r2[1], m);
            r2 += o;
        }
        float mu  = r2[0] * (1.f / 4096.f);
        float var = r2[1] * (1.f / 4096.f) - mu * mu;
        float rsv = rsqrtf(var + 1e-5f) * 1.44269504f;   // rstd*log2e
        float mu2 = mu * rsv;
        f32x4 rs4 = {rsv, rsv, rsv, rsv};
        f32x4 mn4 = {-mu2, -mu2, -mu2, -mu2};

        // exp (mean shift exact-cancels in softmax; |z|<=64 -> no overflow)
        #pragma unroll
        for (int mt = 0; mt < 4; ++mt)
            #pragma unroll
            for (int nt = 0; nt < 4; ++nt) {
                f32x4 tt = __builtin_elementwise_fma(att[mt][nt], rs4, mn4);
                att[mt][nt][0] = __builtin_amdgcn_exp2f(tt[0]);
                att[mt][nt][1] = __builtin_amdgcn_exp2f(tt[1]);
                att[mt][nt][2] = __builtin_amdgcn_exp2f(tt[2]);
                att[mt][nt][3] = __builtin_amdgcn_exp2f(tt[3]);
            }

        // V B-frags for this map; cols 8+ = ones (row-sum column)
        short8 vb[2];
        {
            int n_ = l15 & 7;
            #pragma unroll
            for (int kt = 0; kt < 2; ++kt) {
                short8 x = *(const short8*)&v_w[pp * 512 + n_ * 64 +
                                                ((kt * 32 + g * 8) ^ ((n_ & 3) << 4))];
                vb[kt] = (l15 >= 8) ? ones : x;
            }
        }

        // PV per c-quarter through this map's dead q/k slices
        u16* rowbase = (((l15 < 8) ? (q_w + pp * 512) : (k_w + pp * 512))
                        + (l15 & 7) * 64);
        const int swz = (l15 & 7) << 3;
        #pragma unroll
        for (int NT = 0; NT < 4; ++NT) {
            #pragma unroll
            for (int mt = 0; mt < 4; ++mt) {
                uint2 b;
                b.x = pk_rne(att[mt][NT][0], att[mt][NT][1]);
                b.y = pk_rne(att[mt][NT][2], att[mt][NT][3]);
                *(uint2*)&rowbase[(mt * 16 + g * 4) ^ swz] = b;
            }
            f32x4 pv = zf;
            __builtin_amdgcn_s_setprio(1);
            #pragma unroll
            for (int kt = 0; kt < 2; ++kt) {
                short8 aa = *(const short8*)&rowbase[(kt * 32 + g * 8) ^ swz];
                pv = MFMA(aa, vb[kt], pv);
            }
            __builtin_amdgcn_s_setprio(0);
            // normalize: row sums in col 8 -> lane (g<<4)|8
            int srcl = (l & 48) | 8;
            #pragma unroll
            for (int r = 0; r < 4; ++r) {
                float rsum = __shfl(pv[r], srcl);
                pv[r] *= __builtin_amdgcn_rcpf(rsum);
            }
            // ctx[pp][NT][r]: c = NT*16 + g*4 + r, n = l15 (valid for l15<8)
            ctx[pp][NT] = pv;
        }
    }

    // ---- ctx -> ctxA stripe (WAVE-PRIVATE: own dead q slice, no barrier) ----
    // stripe w @ arena + w*1024: [16 m][64 c], elem c at c ^ ((m&7)<<3).
    {
        u16* ctxS = arena + w * 1024;
        if (l15 < 8) {
            #pragma unroll
            for (int pp = 0; pp < 2; ++pp) {
                int m = pp * 8 + l15;
                int swz2 = (l15 & 7) << 3;     // (m&7)<<3, m&7 == l15
                #pragma unroll
                for (int MT = 0; MT < 4; ++MT) {
                    int c0 = MT * 16 + g * 4;
                    uint2 b;
                    b.x = pk_rne(ctx[pp][MT][0], ctx[pp][MT][1]);
                    b.y = pk_rne(ctx[pp][MT][2], ctx[pp][MT][3]);
                    *(uint2*)&ctxS[m * 64 + (c0 ^ swz2)] = b;
                }
            }
        }
    }
    __syncthreads();   // cross-wave ctxA reads below

    // ---- P3: out = ctx @ Wo (head-major K, split-K over wave pairs) ----
    {
        int nt  = w & 3;
        int kb0 = (w >> 2) * 8;
        int m   = l15;
        f32x4 oacc = {0.f, 0.f, 0.f, 0.f};
        #pragma unroll
        for (int ki = 0; ki < 8; ++ki) {
            int kt = kb0 + ki;
            int h  = kt >> 1;                       // stripe (head)
            int off = ((kt & 1) * 32 + g * 8) ^ ((m & 7) << 3);
            short8 ah = *(const short8*)&arena[h * 1024 + m * 64 + off];
            const u16* bb = &wo[(kt * 4 + nt) * 512];
            short8 bh = *(const short8*)&bb[l * 8];
            oacc = MFMA(ah, bh, oacc);
        }
        float* part = (float*)&arena[16384];   // 4 KB over dead v region
        if (w >= 4) *(f32x4*)&part[((w - 4) * 64 + l) * 4] = oacc;
        __syncthreads();
        if (w < 4) {
            f32x4 o2 = *(const f32x4*)&part[(w * 64 + l) * 4];
            oacc += o2;
            int col = nt * 16 + l15;
            int p   = g >> 1;
            int bp  = bp2 * 2 + p;
            int b   = bp / 27, rr = bp % 27;
            int dd  = rr / 9, hh2 = (rr / 3) % 3, ww2 = rr % 3;
            #pragma unroll
            for (int r = 0; r < 4; ++r) {
                int n = (g & 1) * 4 + r;
                int token = ((((dd * 2 + (n >> 2)) * 3 + hh2) * 2 + ((n >> 1) & 1)) * 3
                             + ww2) * 2 + (n & 1);
                out[((size_t)b * 216 + token) * 64 + col] = oacc[r];
            }
        }
    }
}

// ---------------------------------------------------------------------------
// fallback (round-2 kernel) if ws is too small for weight preconversion
// ---------------------------------------------------------------------------
__global__ __launch_bounds__(512) void fused_fallback(
    const float* __restrict__ emb, const float* __restrict__ Wq,
    const float* __restrict__ Wk,  const float* __restrict__ Wv,
    const float* __restrict__ Wo,  float* __restrict__ out)
{
    __shared__ float emb_s[512];
    __shared__ float part_sum[64];
    __shared__ float part_ssq[64];
    __shared__ float kv_s[2 * 512 * 8];
    float* k_s = kv_s;
    float* v_s = kv_s + 512 * 8;
    float* ctx_s = kv_s;
    const int bp = blockIdx.x;
    const int t  = threadIdx.x;
    emb_s[t] = emb[bp * 512 + t];
    __syncthreads();
    float q[8];
    {
        float ak[8], av[8];
        #pragma unroll
        for (int n = 0; n < 8; ++n) { q[n] = 0.f; ak[n] = 0.f; av[n] = 0.f; }
        #pragma unroll 8
        for (int j = 0; j < 64; ++j) {
            const float wq = Wq[j * 512 + t], wk = Wk[j * 512 + t], wv = Wv[j * 512 + t];
            #pragma unroll
            for (int n = 0; n < 8; ++n) {
                const float e = emb_s[n * 64 + j];
                q[n] += e * wq; ak[n] += e * wk; av[n] += e * wv;
            }
        }
        float4* kd = (float4*)&k_s[t * 8];
        float4* vd = (float4*)&v_s[t * 8];
        kd[0] = make_float4(ak[0], ak[1], ak[2], ak[3]);
        kd[1] = make_float4(ak[4], ak[5], ak[6], ak[7]);
        vd[0] = make_float4(av[0], av[1], av[2], av[3]);
        vd[1] = make_float4(av[4], av[5], av[6], av[7]);
    }
    __syncthreads();
    const int h = t & 7;
    float arow[64];
    float sum = 0.f, ssq = 0.f;
    #pragma unroll
    for (int d = 0; d < 64; ++d) {
        const float4* kr = (const float4*)&k_s[(d * 8 + h) * 8];
        const float4 k0 = kr[0], k1 = kr[1];
        float s = q[0]*k0.x + q[1]*k0.y + q[2]*k0.z + q[3]*k0.w
                + q[4]*k1.x + q[5]*k1.y + q[6]*k1.z + q[7]*k1.w;
        arow[d] = s; sum += s; ssq += s * s;
    }
    #pragma unroll
    for (int m = 8; m < 64; m <<= 1) { sum += __shfl_xor(sum, m); ssq += __shfl_xor(ssq, m); }
    const int wv_id = t >> 6;
    if ((t & 63) < 8) { part_sum[wv_id * 8 + h] = sum; part_ssq[wv_id * 8 + h] = ssq; }
    __syncthreads();
    sum = 0.f; ssq = 0.f;
    #pragma unroll
    for (int w2 = 0; w2 < 8; ++w2) { sum += part_sum[w2 * 8 + h]; ssq += part_ssq[w2 * 8 + h]; }
    const float mean = sum * (1.f / 4096.f);
    const float var  = ssq * (1.f / 4096.f) - mean * mean;
    const float rstd = rsqrtf(var + 1e-5f);
    float mx = -3.0e38f;
    #pragma unroll
    for (int d = 0; d < 64; ++d) { arow[d] = (arow[d] - mean) * rstd; mx = fmaxf(mx, arow[d]); }
    float es = 0.f;
    #pragma unroll
    for (int d = 0; d < 64; ++d) { arow[d] = __expf(arow[d] - mx); es += arow[d]; }
    const float inv = 1.f / es;
    float c[8];
    #pragma unroll
    for (int n = 0; n < 8; ++n) c[n] = 0.f;
    #pragma unroll
    for (int d = 0; d < 64; ++d) {
        const float4* vr = (const float4*)&v_s[(d * 8 + h) * 8];
        const float4 v0 = vr[0], v1 = vr[1];
        const float a = arow[d] * inv;
        c[0]+=a*v0.x; c[1]+=a*v0.y; c[2]+=a*v0.z; c[3]+=a*v0.w;
        c[4]+=a*v1.x; c[5]+=a*v1.y; c[6]+=a*v1.z; c[7]+=a*v1.w;
    }
    __syncthreads();
    #pragma unroll
    for (int n = 0; n < 8; ++n) ctx_s[n * 512 + t] = c[n];
    __syncthreads();
    const int n_o = t >> 6, gg = t & 15, ss = (t >> 4) & 3;
    const float4* Wo4 = (const float4*)Wo;
    const float4* cx4 = (const float4*)&ctx_s[n_o * 512 + ss * 128];
    float4 acc = make_float4(0.f, 0.f, 0.f, 0.f);
    #pragma unroll 8
    for (int kk = 0; kk < 128; kk += 4) {
        const float4 cc = cx4[kk >> 2];
        const int kbm = (ss * 128 + kk) * 16 + gg;
        const float4 w0 = Wo4[kbm], w1 = Wo4[kbm + 16], w2 = Wo4[kbm + 32], w3_ = Wo4[kbm + 48];
        acc.x += cc.x*w0.x + cc.y*w1.x + cc.z*w2.x + cc.w*w3_.x;
        acc.y += cc.x*w0.y + cc.y*w1.y + cc.z*w2.y + cc.w*w3_.y;
        acc.z += cc.x*w0.z + cc.y*w1.z + cc.z*w2.z + cc.w*w3_.z;
        acc.w += cc.x*w0.w + cc.y*w1.w + cc.z*w2.w + cc.w*w3_.w;
    }
    acc.x += __shfl_xor(acc.x, 16); acc.x += __shfl_xor(acc.x, 32);
    acc.y += __shfl_xor(acc.y, 16); acc.y += __shfl_xor(acc.y, 32);
    acc.z += __shfl_xor(acc.z, 16); acc.z += __shfl_xor(acc.z, 32);
    acc.w += __shfl_xor(acc.w, 16); acc.w += __shfl_xor(acc.w, 32);
    if (ss == 0) {
        const int b = bp / 27, r = bp % 27;
        const int dd = r / 9, hh = (r / 3) % 3, ww = r % 3;
        const int token = ((((dd*2 + ((n_o>>2)&1))*3 + hh)*2 + ((n_o>>1)&1))*3 + ww)*2 + (n_o&1);
        *(float4*)&out[(b * 216 + token) * 64 + gg * 4] = acc;
    }
}

extern "C" void kernel_launch(void* const* d_in, const int* in_sizes, int n_in,
                              void* d_out, int out_size, void* d_ws, size_t ws_size,
                              hipStream_t stream) {
    const float* emb = (const float*)d_in[0];
    const float* Wq  = (const float*)d_in[1];
    const float* Wk  = (const float*)d_in[2];
    const float* Wv  = (const float*)d_in[3];
    const float* Wo  = (const float*)d_in[4];
    float* out = (float*)d_out;
    const int Bp = in_sizes[0] / 512;   // 3456

    if (ws_size >= 131072 * sizeof(u16) && (Bp & 1) == 0) {
        u16* ws = (u16*)d_ws;
        prep_weights<<<256, 512, 0, stream>>>(Wq, Wk, Wv, Wo, ws);
        fused_attn_mfma<<<Bp / 2, 512, 0, stream>>>(emb, ws, ws + 98304, out);
    } else {
        fused_fallback<<<Bp, 512, 0, stream>>>(emb, Wq, Wk, Wv, Wo, out);
    }
}